// Round 4
// baseline (64199.683 us; speedup 1.0000x reference)
//
#include <hip/hip_runtime.h>
#include <stddef.h>
#include <stdint.h>

// Problem dims (fixed by the reference)
#define BB 32
#define TT 2048
#define NI 128
#define NH 512
#define NO 128

// d_out layout (floats): z[BB*NO] | X[BB*TT*NH] | As[BB*TT*NH] | Phis[BB*TT*NH]
#define Z_OFS   0
#define X_OFS   (BB * NO)
#define AS_OFS  (X_OFS + (size_t)BB * TT * NH)
#define PHI_OFS (AS_OFS + (size_t)BB * TT * NH)

// Scan: ONE workgroup per batch. Whole Wr (1 MB f32) resident in the CU's
// 2 MB unified register file: 1024 threads x 256 f32 (64 float4) each.
// Thread (g,hh): rows h = hh*8..hh*8+7, cols k = g*32..g*32+31.
#define RPT 8                  // rows per thread
#define CPT 32                 // cols per thread
#define NGR (NH / CPT)         // 16 k-groups
#define NTHR 1024

typedef float f32x2 __attribute__((ext_vector_type(2)));

// ---------------------------------------------------------------------------
// Kernel 1: ui[bt][h] = sum_k u[bt][k] * Wi[h][k]   (written into As region)
// ---------------------------------------------------------------------------
__global__ void __launch_bounds__(256) ui_gemm(const float* __restrict__ u,
                                               const float* __restrict__ Wi,
                                               float* __restrict__ ui_out) {
    __shared__ float Au[64][NI + 1];
    __shared__ float Bw[64][NI + 1];
    const int tid = threadIdx.x;
    const int bt0 = blockIdx.x * 64;
    const int h0  = blockIdx.y * 64;

    for (int idx = tid; idx < 64 * (NI / 4); idx += 256) {
        const int r = idx >> 5;
        const int c = (idx & 31) << 2;
        float4 va = *reinterpret_cast<const float4*>(&u[(size_t)(bt0 + r) * NI + c]);
        Au[r][c + 0] = va.x; Au[r][c + 1] = va.y; Au[r][c + 2] = va.z; Au[r][c + 3] = va.w;
        float4 vb = *reinterpret_cast<const float4*>(&Wi[(size_t)(h0 + r) * NI + c]);
        Bw[r][c + 0] = vb.x; Bw[r][c + 1] = vb.y; Bw[r][c + 2] = vb.z; Bw[r][c + 3] = vb.w;
    }
    __syncthreads();

    const int tx = tid & 15;
    const int ty = tid >> 4;
    float acc[4][4] = {};
    for (int k = 0; k < NI; ++k) {
        float a_[4], b_[4];
#pragma unroll
        for (int i = 0; i < 4; ++i) a_[i] = Au[ty * 4 + i][k];
#pragma unroll
        for (int j = 0; j < 4; ++j) b_[j] = Bw[tx * 4 + j][k];
#pragma unroll
        for (int i = 0; i < 4; ++i)
#pragma unroll
            for (int j = 0; j < 4; ++j) acc[i][j] += a_[i] * b_[j];
    }
#pragma unroll
    for (int i = 0; i < 4; ++i)
#pragma unroll
        for (int j = 0; j < 4; ++j)
            ui_out[(size_t)(bt0 + ty * 4 + i) * NH + (h0 + tx * 4 + j)] = acc[i][j];
}

// ---------------------------------------------------------------------------
// Kernel 2: single-WG-per-batch scan, weights register-resident.
// ---------------------------------------------------------------------------
__global__ void __launch_bounds__(NTHR) rnn_scan_res(const float* __restrict__ Wr,
                                                     float* __restrict__ out) {
    const int b   = blockIdx.x;
    const int tid = threadIdx.x;
    const int g   = tid >> 6;     // k-group 0..15, uniform within a wave
    const int hh  = tid & 63;     // row-block; rows h = hh*8 .. hh*8+7

    __shared__ float x_lds[NH];          // 2 KB
    __shared__ float part[NGR][NH];      // 32 KB

    // ---- Load this thread's 8x32 weight block into 64 float4 registers.
    float4 w[RPT * 8];
    {
        const float* wbase = Wr + (size_t)(hh * RPT) * NH + g * CPT;
#pragma unroll
        for (int r = 0; r < RPT; ++r)
#pragma unroll
            for (int i = 0; i < 8; ++i)
                w[r * 8 + i] =
                    *reinterpret_cast<const float4*>(&wbase[(size_t)r * NH + i * 4]);
        // Pin: values originate at this asm -> loads cannot be re-sunk into
        // the loop (R2 failure mode). gfx950 VALU reads AGPR operands
        // directly, so unified-file placement is fine.
#pragma unroll
        for (int i = 0; i < RPT * 8; ++i)
            asm volatile("" : "+v"(w[i].x), "+v"(w[i].y), "+v"(w[i].z), "+v"(w[i].w));
    }

    float* __restrict__ Xp  = out + X_OFS   + (size_t)b * TT * NH;
    float* __restrict__ Asp = out + AS_OFS  + (size_t)b * TT * NH;
    float* __restrict__ Php = out + PHI_OFS + (size_t)b * TT * NH;

    // x0 = 0; prefetch ui for t=0
    float uival = 0.0f;
    if (tid < NH) {
        x_lds[tid] = 0.0f;
        uival = Asp[tid];
    }
    __syncthreads();

    for (int t = 0; t < TT; ++t) {
        // ---- dot: 8 rows x 32 cols per thread, packed-f32 FMA
        f32x2 acc[RPT];
#pragma unroll
        for (int r = 0; r < RPT; ++r) acc[r] = (f32x2){0.0f, 0.0f};

#pragma unroll
        for (int i = 0; i < 8; ++i) {
            float4 xv = *reinterpret_cast<const float4*>(&x_lds[g * CPT + i * 4]);
            f32x2 xa = {xv.x, xv.y};
            f32x2 xb = {xv.z, xv.w};
#pragma unroll
            for (int r = 0; r < RPT; ++r) {
                const float4& ww = w[r * 8 + i];
                f32x2 wa = {ww.x, ww.y};
                f32x2 wb = {ww.z, ww.w};
                acc[r] = __builtin_elementwise_fma(wa, xa, acc[r]);
                acc[r] = __builtin_elementwise_fma(wb, xb, acc[r]);
            }
        }

        // ---- stash partials: part[g][hh*8 .. hh*8+7]
        float4 p0, p1;
        p0.x = acc[0][0] + acc[0][1];
        p0.y = acc[1][0] + acc[1][1];
        p0.z = acc[2][0] + acc[2][1];
        p0.w = acc[3][0] + acc[3][1];
        p1.x = acc[4][0] + acc[4][1];
        p1.y = acc[5][0] + acc[5][1];
        p1.z = acc[6][0] + acc[6][1];
        p1.w = acc[7][0] + acc[7][1];
        *reinterpret_cast<float4*>(&part[g][hh * RPT])     = p0;
        *reinterpret_cast<float4*>(&part[g][hh * RPT + 4]) = p1;
        __syncthreads();

        // ---- reduce + tanh + emit (threads 0..511 own one h each)
        if (tid < NH) {
            const size_t o = (size_t)t * NH + tid;
            float a = uival;
#pragma unroll
            for (int gg = 0; gg < NGR; ++gg) a += part[gg][tid];
            const float phi = tanhf(a);
            x_lds[tid] = phi;              // next step's state (post-barrier ok)
            Asp[o] = a;
            Xp [o] = phi;
            Php[o] = phi;
            if (t + 1 < TT) uival = Asp[o + NH];   // prefetch next ui
        }
        __syncthreads();
    }
}

// ---------------------------------------------------------------------------
// Kernel 3: z[b][o] = sum_h X[b][T-1][h] * Wo[o][h]
// ---------------------------------------------------------------------------
__global__ void __launch_bounds__(128) z_gemv(const float* __restrict__ Wo,
                                              float* __restrict__ out) {
    const int b = blockIdx.x;
    const int o = threadIdx.x;
    __shared__ float xl[NH];
    const float* Xlast = out + X_OFS + (size_t)b * TT * NH + (size_t)(TT - 1) * NH;
    for (int h = threadIdx.x; h < NH; h += 128) xl[h] = Xlast[h];
    __syncthreads();
    float acc = 0.f;
#pragma unroll 4
    for (int h4 = 0; h4 < NH / 4; ++h4) {
        float4 w = *reinterpret_cast<const float4*>(&Wo[(size_t)o * NH + h4 * 4]);
        acc += xl[h4 * 4 + 0] * w.x + xl[h4 * 4 + 1] * w.y +
               xl[h4 * 4 + 2] * w.z + xl[h4 * 4 + 3] * w.w;
    }
    out[Z_OFS + (size_t)b * NO + o] = acc;
}

// ---------------------------------------------------------------------------
extern "C" void kernel_launch(void* const* d_in, const int* in_sizes, int n_in,
                              void* d_out, int out_size, void* d_ws, size_t ws_size,
                              hipStream_t stream) {
    const float* u  = (const float*)d_in[0];
    const float* Wr = (const float*)d_in[1];
    const float* Wi = (const float*)d_in[2];
    const float* Wo = (const float*)d_in[3];
    float* out = (float*)d_out;

    // ui -> As region of d_out (scan reads it there, then overwrites with a)
    ui_gemm<<<dim3((BB * TT) / 64, NH / 64), 256, 0, stream>>>(u, Wi, out + AS_OFS);

    rnn_scan_res<<<BB, NTHR, 0, stream>>>(Wr, out);

    z_gemv<<<BB, 128, 0, stream>>>(Wo, out);
}

// Round 5
// 46913.589 us; speedup vs baseline: 1.3685x; 1.3685x over previous
//
#include <hip/hip_runtime.h>
#include <stddef.h>
#include <stdint.h>

// Problem dims (fixed by the reference)
#define BB 32
#define TT 2048
#define NI 128
#define NH 512
#define NO 128

// d_out layout (floats): z[BB*NO] | X[BB*TT*NH] | As[BB*TT*NH] | Phis[BB*TT*NH]
#define Z_OFS   0
#define X_OFS   (BB * NO)
#define AS_OFS  (X_OFS + (size_t)BB * TT * NH)
#define PHI_OFS (AS_OFS + (size_t)BB * TT * NH)

// Scan: ONE workgroup per batch, full Wr register-resident (1 MB f32 over
// 1024 threads = 256 f32 = 128 f32x2 per thread). Thread (g,hh):
// rows h = hh*8..hh*8+7, cols k = g*32..g*32+31.
#define RPT 8                  // rows per thread
#define CPT 32                 // cols per thread
#define NGR (NH / CPT)         // 16 k-groups
#define NTHR 1024

typedef float f32x2 __attribute__((ext_vector_type(2)));
typedef float f32x4 __attribute__((ext_vector_type(4)));

// ---------------------------------------------------------------------------
// Kernel 1: ui[bt][h] = sum_k u[bt][k] * Wi[h][k]   (written into As region)
// ---------------------------------------------------------------------------
__global__ void __launch_bounds__(256) ui_gemm(const float* __restrict__ u,
                                               const float* __restrict__ Wi,
                                               float* __restrict__ ui_out) {
    __shared__ float Au[64][NI + 1];
    __shared__ float Bw[64][NI + 1];
    const int tid = threadIdx.x;
    const int bt0 = blockIdx.x * 64;
    const int h0  = blockIdx.y * 64;

    for (int idx = tid; idx < 64 * (NI / 4); idx += 256) {
        const int r = idx >> 5;
        const int c = (idx & 31) << 2;
        float4 va = *reinterpret_cast<const float4*>(&u[(size_t)(bt0 + r) * NI + c]);
        Au[r][c + 0] = va.x; Au[r][c + 1] = va.y; Au[r][c + 2] = va.z; Au[r][c + 3] = va.w;
        float4 vb = *reinterpret_cast<const float4*>(&Wi[(size_t)(h0 + r) * NI + c]);
        Bw[r][c + 0] = vb.x; Bw[r][c + 1] = vb.y; Bw[r][c + 2] = vb.z; Bw[r][c + 3] = vb.w;
    }
    __syncthreads();

    const int tx = tid & 15;
    const int ty = tid >> 4;
    float acc[4][4] = {};
    for (int k = 0; k < NI; ++k) {
        float a_[4], b_[4];
#pragma unroll
        for (int i = 0; i < 4; ++i) a_[i] = Au[ty * 4 + i][k];
#pragma unroll
        for (int j = 0; j < 4; ++j) b_[j] = Bw[tx * 4 + j][k];
#pragma unroll
        for (int i = 0; i < 4; ++i)
#pragma unroll
            for (int j = 0; j < 4; ++j) acc[i][j] += a_[i] * b_[j];
    }
#pragma unroll
    for (int i = 0; i < 4; ++i)
#pragma unroll
        for (int j = 0; j < 4; ++j)
            ui_out[(size_t)(bt0 + ty * 4 + i) * NH + (h0 + tx * 4 + j)] = acc[i][j];
}

// ---------------------------------------------------------------------------
// Kernel 2: single-WG-per-batch scan, weights register-resident as f32x2.
// ---------------------------------------------------------------------------
__global__ void __launch_bounds__(NTHR)
__attribute__((amdgpu_waves_per_eu(4, 4)))
rnn_scan_res(const float* __restrict__ Wr, float* __restrict__ out) {
    const int b   = blockIdx.x;
    const int tid = threadIdx.x;
    const int g   = tid >> 6;     // k-group 0..15 (wave-uniform)
    const int hh  = tid & 63;     // row-block; rows h = hh*8 .. hh*8+7

    __shared__ float x_lds[NH];          // 2 KB
    __shared__ float part[NGR][NH];      // 32 KB

    // ---- Load this thread's 8x32 weight block into 128 f32x2 registers.
    f32x2 w2[RPT * 16];
    {
        const float* wbase = Wr + (size_t)(hh * RPT) * NH + g * CPT;
#pragma unroll
        for (int r = 0; r < RPT; ++r)
#pragma unroll
            for (int i = 0; i < 8; ++i) {
                float4 t = *reinterpret_cast<const float4*>(
                    &wbase[(size_t)r * NH + i * 4]);
                w2[r * 16 + 2 * i]     = (f32x2){t.x, t.y};
                w2[r * 16 + 2 * i + 1] = (f32x2){t.z, t.w};
            }
        // Pin each f32x2 as a whole 64-bit register operand (no element
        // lvalues -> no alloca; R4's scratch-spill failure mode).
#pragma unroll
        for (int i = 0; i < RPT * 16; ++i)
            asm volatile("" : "+v"(w2[i]));
    }

    float* __restrict__ Xp  = out + X_OFS   + (size_t)b * TT * NH;
    float* __restrict__ Asp = out + AS_OFS  + (size_t)b * TT * NH;
    float* __restrict__ Php = out + PHI_OFS + (size_t)b * TT * NH;

    // x0 = 0; prefetch ui for t=0 (threads 0..127 own 4 h each)
    f32x4 uival = (f32x4){0.f, 0.f, 0.f, 0.f};
    if (tid < 128) {
        const int h0 = tid * 4;
        *reinterpret_cast<f32x4*>(&x_lds[h0]) = (f32x4){0.f, 0.f, 0.f, 0.f};
        uival = *reinterpret_cast<const f32x4*>(&Asp[h0]);
    }
    __syncthreads();

    const int s4 = (hh & 4);  // XOR-half swizzle bit (as byte offset /4: 0 or 4)

    for (int t = 0; t < TT; ++t) {
        // ---- dot: 8 rows x 32 cols per thread via v_pk_fma_f32
        f32x2 acc2[RPT];
#pragma unroll
        for (int r = 0; r < RPT; ++r) acc2[r] = (f32x2){0.0f, 0.0f};

#pragma unroll
        for (int i = 0; i < 8; ++i) {
            f32x4 xv = *reinterpret_cast<const f32x4*>(&x_lds[g * CPT + i * 4]);
            f32x2 xa = (f32x2){xv.x, xv.y};
            f32x2 xb = (f32x2){xv.z, xv.w};
#pragma unroll
            for (int r = 0; r < RPT; ++r) {
                acc2[r] = __builtin_elementwise_fma(w2[r * 16 + 2 * i],     xa, acc2[r]);
                acc2[r] = __builtin_elementwise_fma(w2[r * 16 + 2 * i + 1], xb, acc2[r]);
            }
        }

        // ---- partials: h = hh*8..+7, halves swapped when (hh>>2)&1 == 1
        f32x4 p0, p1;
        p0.x = acc2[0].x + acc2[0].y;
        p0.y = acc2[1].x + acc2[1].y;
        p0.z = acc2[2].x + acc2[2].y;
        p0.w = acc2[3].x + acc2[3].y;
        p1.x = acc2[4].x + acc2[4].y;
        p1.y = acc2[5].x + acc2[5].y;
        p1.z = acc2[6].x + acc2[6].y;
        p1.w = acc2[7].x + acc2[7].y;
        {
            float* row = &part[g][hh * 8];
            *reinterpret_cast<f32x4*>(row + s4)       = p0;  // s4=0:+0, s4=4:+4
            *reinterpret_cast<f32x4*>(row + (4 - s4)) = p1;
        }
        __syncthreads();

        // ---- reduce + tanh + emit: 128 threads, 4 h each, float4 all the way
        if (tid < 128) {
            const int h0   = tid * 4;
            const int hidx = h0 ^ ((h0 >> 3) & 4);   // un-swizzle
            const size_t o = (size_t)t * NH + h0;

            // prefetch next step's ui early (hide HBM latency under reduce)
            f32x4 nxt = (f32x4){0.f, 0.f, 0.f, 0.f};
            if (t + 1 < TT)
                nxt = *reinterpret_cast<const f32x4*>(&Asp[o + NH]);

            f32x4 a = uival;
#pragma unroll
            for (int gg = 0; gg < NGR; ++gg)
                a += *reinterpret_cast<const f32x4*>(&part[gg][hidx]);

            f32x4 phi;
            phi.x = tanhf(a.x);
            phi.y = tanhf(a.y);
            phi.z = tanhf(a.z);
            phi.w = tanhf(a.w);

            *reinterpret_cast<f32x4*>(&x_lds[h0]) = phi;   // next state
            *reinterpret_cast<f32x4*>(&Asp[o])    = a;
            *reinterpret_cast<f32x4*>(&Xp[o])     = phi;
            *reinterpret_cast<f32x4*>(&Php[o])    = phi;
            uival = nxt;
        }
        __syncthreads();
    }
}

// ---------------------------------------------------------------------------
// Kernel 3: z[b][o] = sum_h X[b][T-1][h] * Wo[o][h]
// ---------------------------------------------------------------------------
__global__ void __launch_bounds__(128) z_gemv(const float* __restrict__ Wo,
                                              float* __restrict__ out) {
    const int b = blockIdx.x;
    const int o = threadIdx.x;
    __shared__ float xl[NH];
    const float* Xlast = out + X_OFS + (size_t)b * TT * NH + (size_t)(TT - 1) * NH;
    for (int h = threadIdx.x; h < NH; h += 128) xl[h] = Xlast[h];
    __syncthreads();
    float acc = 0.f;
#pragma unroll 4
    for (int h4 = 0; h4 < NH / 4; ++h4) {
        float4 w = *reinterpret_cast<const float4*>(&Wo[(size_t)o * NH + h4 * 4]);
        acc += xl[h4 * 4 + 0] * w.x + xl[h4 * 4 + 1] * w.y +
               xl[h4 * 4 + 2] * w.z + xl[h4 * 4 + 3] * w.w;
    }
    out[Z_OFS + (size_t)b * NO + o] = acc;
}

// ---------------------------------------------------------------------------
extern "C" void kernel_launch(void* const* d_in, const int* in_sizes, int n_in,
                              void* d_out, int out_size, void* d_ws, size_t ws_size,
                              hipStream_t stream) {
    const float* u  = (const float*)d_in[0];
    const float* Wr = (const float*)d_in[1];
    const float* Wi = (const float*)d_in[2];
    const float* Wo = (const float*)d_in[3];
    float* out = (float*)d_out;

    // ui -> As region of d_out (scan reads it there, then overwrites with a)
    ui_gemm<<<dim3((BB * TT) / 64, NH / 64), 256, 0, stream>>>(u, Wi, out + AS_OFS);

    rnn_scan_res<<<BB, NTHR, 0, stream>>>(Wr, out);

    z_gemv<<<BB, 128, 0, stream>>>(Wo, out);
}

// Round 6
// 12028.596 us; speedup vs baseline: 5.3373x; 3.9002x over previous
//
#include <hip/hip_runtime.h>
#include <stddef.h>
#include <stdint.h>

// Problem dims (fixed by the reference)
#define BB 32
#define TT 2048
#define NI 128
#define NH 512
#define NO 128

// d_out layout (floats): z[BB*NO] | X[BB*TT*NH] | As[BB*TT*NH] | Phis[BB*TT*NH]
#define Z_OFS   0
#define X_OFS   (BB * NO)
#define AS_OFS  (X_OFS + (size_t)BB * TT * NH)
#define PHI_OFS (AS_OFS + (size_t)BB * TT * NH)

// Scan: 8 WGs per batch; WG owns 64 rows of Wr, LDS-resident in f32 (128 KB).
// 512 threads: r = tid&63 (row within slice), c = tid>>6 (wave = k-chunk).
// Per step each thread does a 64-MAC chunk; partials reduced across waves in
// LDS; wave 0 runs the cross-WG exchange, wave 7 streams outputs, wave 1
// prefetches next ui.
#define WGPB 8
#define ROWS 64
#define NTHR 512

// d_ws layout: xbuf[2][BB][NH] f32 | flags[BB][WGPB] u32 (64B stride)
#define XBUF_BYTES  (2 * BB * NH * 4)
#define FLAG_STRIDE 16
#define FLAG_BYTES  (BB * WGPB * FLAG_STRIDE * 4)

// LDS layout (floats): wlds[16][2048] | xpad[8][68] | part[8][64] | uil[2][64]
#define LDS_FLOATS (16 * 2048 + 8 * 68 + 8 * 64 + 2 * 64)
#define LDS_BYTES  (LDS_FLOATS * 4)

typedef float f32x2 __attribute__((ext_vector_type(2)));

// ---------------------------------------------------------------------------
// Kernel 1: ui[bt][h] = sum_k u[bt][k] * Wi[h][k]   (written into As region)
// ---------------------------------------------------------------------------
__global__ void __launch_bounds__(256) ui_gemm(const float* __restrict__ u,
                                               const float* __restrict__ Wi,
                                               float* __restrict__ ui_out) {
    __shared__ float Au[64][NI + 1];
    __shared__ float Bw[64][NI + 1];
    const int tid = threadIdx.x;
    const int bt0 = blockIdx.x * 64;
    const int h0  = blockIdx.y * 64;

    for (int idx = tid; idx < 64 * (NI / 4); idx += 256) {
        const int r = idx >> 5;
        const int c = (idx & 31) << 2;
        float4 va = *reinterpret_cast<const float4*>(&u[(size_t)(bt0 + r) * NI + c]);
        Au[r][c + 0] = va.x; Au[r][c + 1] = va.y; Au[r][c + 2] = va.z; Au[r][c + 3] = va.w;
        float4 vb = *reinterpret_cast<const float4*>(&Wi[(size_t)(h0 + r) * NI + c]);
        Bw[r][c + 0] = vb.x; Bw[r][c + 1] = vb.y; Bw[r][c + 2] = vb.z; Bw[r][c + 3] = vb.w;
    }
    __syncthreads();

    const int tx = tid & 15;
    const int ty = tid >> 4;
    float acc[4][4] = {};
    for (int k = 0; k < NI; ++k) {
        float a_[4], b_[4];
#pragma unroll
        for (int i = 0; i < 4; ++i) a_[i] = Au[ty * 4 + i][k];
#pragma unroll
        for (int jj = 0; jj < 4; ++jj) b_[jj] = Bw[tx * 4 + jj][k];
#pragma unroll
        for (int i = 0; i < 4; ++i)
#pragma unroll
            for (int jj = 0; jj < 4; ++jj) acc[i][jj] += a_[i] * b_[jj];
    }
#pragma unroll
    for (int i = 0; i < 4; ++i)
#pragma unroll
        for (int jj = 0; jj < 4; ++jj)
            ui_out[(size_t)(bt0 + ty * 4 + i) * NH + (h0 + tx * 4 + jj)] = acc[i][jj];
}

// ---------------------------------------------------------------------------
// Kernel 2: 8-WG-per-batch scan, weights LDS-resident.
// ---------------------------------------------------------------------------
__global__ void __launch_bounds__(NTHR)
rnn_scan8(const float* __restrict__ Wr, float* __restrict__ out,
          float* __restrict__ xbuf, unsigned int* __restrict__ flags) {
    extern __shared__ float smem[];
    float* wlds = smem;                       // [16][2048]  128 KB
    float* xpad = smem + 16 * 2048;           // [8][68]     x, 68-stride chunks
    float* part = xpad + 8 * 68;              // [8][64]
    float* uil  = part + 8 * 64;              // [2][64]

    const int wg  = blockIdx.x;               // j*32 + b  (all j of b: same %8)
    const int b   = wg & (BB - 1);
    const int j   = wg >> 5;                  // 0..7
    const int h0  = j * ROWS;
    const int tid = threadIdx.x;
    const int r   = tid & 63;
    const int c   = tid >> 6;                 // wave id = k-chunk

    // ---- preload weight slice: thread (r,c) owns w[h0+r][c*64 .. c*64+63]
    {
        const float* wsrc = Wr + (size_t)(h0 + r) * NH + c * 64;
#pragma unroll
        for (int i = 0; i < 16; ++i) {
            float4 v = *reinterpret_cast<const float4*>(wsrc + i * 4);
            *reinterpret_cast<float4*>(&wlds[i * 2048 + (tid << 2)]) = v;
        }
    }
    for (int m = tid; m < 8 * 68; m += NTHR) xpad[m] = 0.0f;   // x0 = 0

    float* __restrict__ Xp  = out + X_OFS   + (size_t)b * TT * NH;
    float* __restrict__ Asp = out + AS_OFS  + (size_t)b * TT * NH;
    float* __restrict__ Php = out + PHI_OFS + (size_t)b * TT * NH;

    if (tid < 16) {   // ui[0] -> uil[0]
        float4 v = *reinterpret_cast<const float4*>(&Asp[h0 + tid * 4]);
        *reinterpret_cast<float4*>(&uil[tid * 4]) = v;
    }
    unsigned int* __restrict__ fbase = flags + (size_t)b * WGPB * FLAG_STRIDE;
    __syncthreads();

    for (int t = 0; t < TT; ++t) {
        // ---- FMA: 64 MACs/thread. x-read is wave-uniform (LDS broadcast).
        f32x2 acc = (f32x2){0.0f, 0.0f};
        const float* xrow = &xpad[c * 68];
#pragma unroll
        for (int i = 0; i < 16; ++i) {
            float4 w = *reinterpret_cast<const float4*>(&wlds[i * 2048 + (tid << 2)]);
            float4 x = *reinterpret_cast<const float4*>(&xrow[i * 4]);
            acc = __builtin_elementwise_fma((f32x2){w.x, w.y}, (f32x2){x.x, x.y}, acc);
            acc = __builtin_elementwise_fma((f32x2){w.z, w.w}, (f32x2){x.z, x.w}, acc);
        }
        part[c * 64 + r] = acc.x + acc.y;
        __syncthreads();

        const size_t o = (size_t)t * NH + h0 + r;
        if (c == 0) {
            // ---- exchange critical path (wave 0 only)
            float a = uil[(t & 1) * 64 + r];
#pragma unroll
            for (int cc = 0; cc < 8; ++cc) a += part[cc * 64 + r];
            const float phi = tanhf(a);
            xpad[j * 68 + r] = phi;                       // own chunk, local
            if (t + 1 < TT) {
                xbuf[((size_t)((t + 1) & 1)) * BB * NH + b * NH + h0 + r] = phi;
                asm volatile("s_waitcnt vmcnt(0)" ::: "memory");
                if (r == 0)
                    __hip_atomic_store(&fbase[j * FLAG_STRIDE], (unsigned)(t + 1),
                                       __ATOMIC_RELEASE, __HIP_MEMORY_SCOPE_AGENT);
                if (r < WGPB) {
                    while (__hip_atomic_load(&fbase[r * FLAG_STRIDE],
                                             __ATOMIC_RELAXED,
                                             __HIP_MEMORY_SCOPE_AGENT)
                           < (unsigned)(t + 1)) {}
                }
                __builtin_amdgcn_fence(__ATOMIC_ACQUIRE, "agent");
                // reload full x_{t+1} (512 f32) into padded chunks
                const float* xs = xbuf + ((size_t)((t + 1) & 1)) * BB * NH + b * NH;
                float4 A  = *reinterpret_cast<const float4*>(xs + r * 4);
                float4 Bv = *reinterpret_cast<const float4*>(xs + 256 + r * 4);
                *reinterpret_cast<float4*>(&xpad[(r >> 4) * 68 + (r & 15) * 4]) = A;
                *reinterpret_cast<float4*>(&xpad[(4 + (r >> 4)) * 68 + (r & 15) * 4]) = Bv;
            }
        } else if (c == 7) {
            // ---- output streaming (duplicate reduce, off critical path)
            float a = uil[(t & 1) * 64 + r];
#pragma unroll
            for (int cc = 0; cc < 8; ++cc) a += part[cc * 64 + r];
            const float phi = tanhf(a);
            Asp[o] = a;
            Xp [o] = phi;
            Php[o] = phi;
        } else if (c == 1) {
            // ---- prefetch next ui into the other uil buffer
            if (t + 1 < TT && r < 16) {
                float4 v = *reinterpret_cast<const float4*>(
                    &Asp[(size_t)(t + 1) * NH + h0 + r * 4]);
                *reinterpret_cast<float4*>(&uil[((t + 1) & 1) * 64 + r * 4]) = v;
            }
        }
        __syncthreads();
    }
}

// ---------------------------------------------------------------------------
// Kernel 3: z[b][o] = sum_h X[b][T-1][h] * Wo[o][h]
// ---------------------------------------------------------------------------
__global__ void __launch_bounds__(128) z_gemv(const float* __restrict__ Wo,
                                              float* __restrict__ out) {
    const int b = blockIdx.x;
    const int o = threadIdx.x;
    __shared__ float xl[NH];
    const float* Xlast = out + X_OFS + (size_t)b * TT * NH + (size_t)(TT - 1) * NH;
    for (int h = threadIdx.x; h < NH; h += 128) xl[h] = Xlast[h];
    __syncthreads();
    float acc = 0.f;
#pragma unroll 4
    for (int h4 = 0; h4 < NH / 4; ++h4) {
        float4 w = *reinterpret_cast<const float4*>(&Wo[(size_t)o * NH + h4 * 4]);
        acc += xl[h4 * 4 + 0] * w.x + xl[h4 * 4 + 1] * w.y +
               xl[h4 * 4 + 2] * w.z + xl[h4 * 4 + 3] * w.w;
    }
    out[Z_OFS + (size_t)b * NO + o] = acc;
}

// ---------------------------------------------------------------------------
extern "C" void kernel_launch(void* const* d_in, const int* in_sizes, int n_in,
                              void* d_out, int out_size, void* d_ws, size_t ws_size,
                              hipStream_t stream) {
    const float* u  = (const float*)d_in[0];
    const float* Wr = (const float*)d_in[1];
    const float* Wi = (const float*)d_in[2];
    const float* Wo = (const float*)d_in[3];
    float* out = (float*)d_out;

    float*        xbuf  = (float*)d_ws;
    unsigned int* flags = (unsigned int*)((char*)d_ws + XBUF_BYTES);

    // allow >64KB dynamic LDS (idempotent; host-side, capture-safe)
    static bool attr_set = false;
    if (!attr_set) {
        hipFuncSetAttribute(reinterpret_cast<const void*>(rnn_scan8),
                            hipFuncAttributeMaxDynamicSharedMemorySize, LDS_BYTES);
        attr_set = true;
    }

    // reset xbuf (x0=0) and flags each replay
    hipMemsetAsync(d_ws, 0, XBUF_BYTES + FLAG_BYTES, stream);

    // ui -> As region of d_out (scan reads it there, then overwrites with a)
    ui_gemm<<<dim3((BB * TT) / 64, NH / 64), 256, 0, stream>>>(u, Wi, out + AS_OFS);

    rnn_scan8<<<BB * WGPB, NTHR, LDS_BYTES, stream>>>(Wr, out, xbuf, flags);

    z_gemv<<<BB, 128, 0, stream>>>(Wo, out);
}

// Round 8
// 7569.660 us; speedup vs baseline: 8.4812x; 1.5891x over previous
//
#include <hip/hip_runtime.h>
#include <stddef.h>
#include <stdint.h>

// Problem dims (fixed by the reference)
#define BB 32
#define TT 2048
#define NI 128
#define NH 512
#define NO 128

// d_out layout (floats): z[BB*NO] | X[BB*TT*NH] | As[BB*TT*NH] | Phis[BB*TT*NH]
#define Z_OFS   0
#define X_OFS   (BB * NO)
#define AS_OFS  (X_OFS + (size_t)BB * TT * NH)
#define PHI_OFS (AS_OFS + (size_t)BB * TT * NH)

// Scan: 4 WGs per batch (128 WGs, 512 thr each -> 8 waves @ ~180 VGPR ->
// exactly 1 WG/CU, guaranteed co-residency on 256 CUs). Each thread owns one
// 128-col stripe of one Wr row: 64 f32x2 pinned registers (128 VGPR of the
// 256 budget at 512 threads). Wave 0 owns the exchange critical path; waves
// 2-3 duplicate the cheap reduce and stream outputs (deferred one phase).
#define WGPB 4
#define ROWS 128               // rows per WG
#define NTHR 512

// d_ws: xbuf[2][BB][NH] f32 | flags[BB][WGPB] u32 (64 B apart)
#define XBUF_BYTES  (2 * BB * NH * 4)
#define FLAG_STRIDE 16
#define FLAG_BYTES  (BB * WGPB * FLAG_STRIDE * 4)

typedef float f32x2 __attribute__((ext_vector_type(2)));

// ---------------------------------------------------------------------------
// Kernel 1: ui[bt][h] = sum_k u[bt][k] * Wi[h][k]   (written into As region)
// ---------------------------------------------------------------------------
__global__ void __launch_bounds__(256) ui_gemm(const float* __restrict__ u,
                                               const float* __restrict__ Wi,
                                               float* __restrict__ ui_out) {
    __shared__ float Au[64][NI + 1];
    __shared__ float Bw[64][NI + 1];
    const int tid = threadIdx.x;
    const int bt0 = blockIdx.x * 64;
    const int h0  = blockIdx.y * 64;

    for (int idx = tid; idx < 64 * (NI / 4); idx += 256) {
        const int r = idx >> 5;
        const int c = (idx & 31) << 2;
        float4 va = *reinterpret_cast<const float4*>(&u[(size_t)(bt0 + r) * NI + c]);
        Au[r][c + 0] = va.x; Au[r][c + 1] = va.y; Au[r][c + 2] = va.z; Au[r][c + 3] = va.w;
        float4 vb = *reinterpret_cast<const float4*>(&Wi[(size_t)(h0 + r) * NI + c]);
        Bw[r][c + 0] = vb.x; Bw[r][c + 1] = vb.y; Bw[r][c + 2] = vb.z; Bw[r][c + 3] = vb.w;
    }
    __syncthreads();

    const int tx = tid & 15;
    const int ty = tid >> 4;
    float acc[4][4] = {};
    for (int k = 0; k < NI; ++k) {
        float a_[4], b_[4];
#pragma unroll
        for (int i = 0; i < 4; ++i) a_[i] = Au[ty * 4 + i][k];
#pragma unroll
        for (int jj = 0; jj < 4; ++jj) b_[jj] = Bw[tx * 4 + jj][k];
#pragma unroll
        for (int i = 0; i < 4; ++i)
#pragma unroll
            for (int jj = 0; jj < 4; ++jj) acc[i][jj] += a_[i] * b_[jj];
    }
#pragma unroll
    for (int i = 0; i < 4; ++i)
#pragma unroll
        for (int jj = 0; jj < 4; ++jj)
            ui_out[(size_t)(bt0 + ty * 4 + i) * NH + (h0 + tx * 4 + jj)] = acc[i][jj];
}

// ---------------------------------------------------------------------------
// Kernel 2: 4-WG-per-batch scan, register-resident weights, lean wave-0 sync.
// ---------------------------------------------------------------------------
__global__ void __launch_bounds__(NTHR)
rnn_scan4(const float* __restrict__ Wr, float* __restrict__ out,
          float* __restrict__ xbuf, unsigned int* __restrict__ flags) {
    const int blk = blockIdx.x;            // j*32 + b  -> blk%8 == b%8:
    const int b   = blk & (BB - 1);        //   all 4 WGs of a batch on one XCD
    const int j   = blk >> 5;              // 0..3
    const int h0  = j * ROWS;
    const int tid = threadIdx.x;
    const int q   = tid & 127;             // row within slice
    const int g   = tid >> 7;              // col group: cols [g*128, g*128+128)
    const int l   = tid & 63;              // lane
    const int wv  = tid >> 6;              // wave 0..7

    __shared__ float x_lds[NH];            // 2 KB
    __shared__ float part[WGPB][ROWS];     // 2 KB

    // ---- weights: row h0+q, cols [g*128, g*128+128) -> 64 pinned f32x2
    f32x2 w2[64];
    {
        const float* wrow = Wr + (size_t)(h0 + q) * NH + g * 128;
#pragma unroll
        for (int i = 0; i < 64; ++i)
            w2[i] = *reinterpret_cast<const f32x2*>(&wrow[2 * i]);
#pragma unroll
        for (int i = 0; i < 64; ++i)
            asm volatile("" : "+v"(w2[i]));
    }

    float* __restrict__ Xp  = out + X_OFS   + (size_t)b * TT * NH;
    float* __restrict__ Asp = out + AS_OFS  + (size_t)b * TT * NH;
    float* __restrict__ Php = out + PHI_OFS + (size_t)b * TT * NH;
    unsigned int* __restrict__ fb = flags + (size_t)b * WGPB * FLAG_STRIDE;

    x_lds[tid & (NH - 1)] = 0.0f;          // x0 = 0 (512 threads = NH)

    // ui prefetch for t=0
    f32x2 ui0 = {0.f, 0.f};                // wave 0: rows 2l, 2l+1
    float ui1 = 0.f;                       // waves 2,3: row tid-128
    if (wv == 0) ui0 = *reinterpret_cast<const f32x2*>(&Asp[h0 + 2 * l]);
    else if (wv == 2 || wv == 3) ui1 = Asp[h0 + (tid - 128)];

    // deferred output state (waves 2,3)
    float pa = 0.f, pph = 0.f;
    size_t po = 0;

    __syncthreads();

    for (int t = 0; t < TT; ++t) {
        // ================= phase A: deferred stores + prefetch + FMA ======
        if ((wv == 2 || wv == 3) && t > 0) {
            Asp[po] = pa; Xp[po] = pph; Php[po] = pph;
        }
        f32x2 nui0 = {0.f, 0.f};
        float nui1 = 0.f;
        if (t + 1 < TT) {
            if (wv == 0)
                nui0 = *reinterpret_cast<const f32x2*>(
                    &Asp[(size_t)(t + 1) * NH + h0 + 2 * l]);
            else if (wv == 2 || wv == 3)
                nui1 = Asp[(size_t)(t + 1) * NH + h0 + (tid - 128)];
        }

        f32x2 acc = {0.f, 0.f};
        const float* xg = &x_lds[g * 128];  // wave-uniform -> LDS broadcast
#pragma unroll
        for (int i = 0; i < 32; ++i) {
            float4 xv = *reinterpret_cast<const float4*>(&xg[4 * i]);
            acc = __builtin_elementwise_fma(w2[2 * i],     (f32x2){xv.x, xv.y}, acc);
            acc = __builtin_elementwise_fma(w2[2 * i + 1], (f32x2){xv.z, xv.w}, acc);
        }
        part[g][q] = acc.x + acc.y;
        __syncthreads();

        // ================= phase B ========================================
        if (wv == 0) {
            // critical path: reduce 2 rows -> tanh -> exchange
            f32x2 a2 = ui0;
#pragma unroll
            for (int cc = 0; cc < WGPB; ++cc)
                a2 += *reinterpret_cast<const f32x2*>(&part[cc][2 * l]);
            f32x2 ph;
            ph.x = tanhf(a2.x);
            ph.y = tanhf(a2.y);
            *reinterpret_cast<f32x2*>(&x_lds[h0 + 2 * l]) = ph;   // own slice
            if (t + 1 < TT) {
                const size_t bs = (size_t)((t + 1) & 1);
                *reinterpret_cast<f32x2*>(
                    &xbuf[(bs * BB + b) * NH + h0 + 2 * l]) = ph;
                if (l == 0)   // RELEASE: waits this wave's vmcnt, then flags
                    __hip_atomic_store(&fb[j * FLAG_STRIDE], (unsigned)(t + 1),
                                       __ATOMIC_RELEASE, __HIP_MEMORY_SCOPE_AGENT);
                if (l < WGPB - 1) {   // lanes 0..2 poll the 3 peers
                    const int jj = l + (l >= j);
                    while (__hip_atomic_load(&fb[jj * FLAG_STRIDE],
                                             __ATOMIC_RELAXED,
                                             __HIP_MEMORY_SCOPE_AGENT)
                           < (unsigned)(t + 1)) {}
                }
                __builtin_amdgcn_fence(__ATOMIC_ACQUIRE, "agent");
#pragma unroll
                for (int s = 0; s < WGPB - 1; ++s) {
                    const int jj = s + (s >= j);
                    f32x2 v = *reinterpret_cast<const f32x2*>(
                        &xbuf[(bs * BB + b) * NH + jj * ROWS + 2 * l]);
                    *reinterpret_cast<f32x2*>(&x_lds[jj * ROWS + 2 * l]) = v;
                }
            }
            ui0 = nui0;
        } else if (wv == 2 || wv == 3) {
            // shadow path: duplicate reduce, defer stores to next phase A
            const int rr = tid - 128;
            float a = ui1;
#pragma unroll
            for (int cc = 0; cc < WGPB; ++cc) a += part[cc][rr];
            pa  = a;
            pph = tanhf(a);
            po  = (size_t)t * NH + h0 + rr;
            ui1 = nui1;
        }
        __syncthreads();
    }

    // final deferred outputs (t = TT-1)
    if (wv == 2 || wv == 3) {
        Asp[po] = pa; Xp[po] = pph; Php[po] = pph;
    }
}

// ---------------------------------------------------------------------------
// Kernel 3: z[b][o] = sum_h X[b][T-1][h] * Wo[o][h]
// ---------------------------------------------------------------------------
__global__ void __launch_bounds__(128) z_gemv(const float* __restrict__ Wo,
                                              float* __restrict__ out) {
    const int b = blockIdx.x;
    const int o = threadIdx.x;
    __shared__ float xl[NH];
    const float* Xlast = out + X_OFS + (size_t)b * TT * NH + (size_t)(TT - 1) * NH;
    for (int h = threadIdx.x; h < NH; h += 128) xl[h] = Xlast[h];
    __syncthreads();
    float acc = 0.f;
#pragma unroll 4
    for (int h4 = 0; h4 < NH / 4; ++h4) {
        float4 w = *reinterpret_cast<const float4*>(&Wo[(size_t)o * NH + h4 * 4]);
        acc += xl[h4 * 4 + 0] * w.x + xl[h4 * 4 + 1] * w.y +
               xl[h4 * 4 + 2] * w.z + xl[h4 * 4 + 3] * w.w;
    }
    out[Z_OFS + (size_t)b * NO + o] = acc;
}

// ---------------------------------------------------------------------------
extern "C" void kernel_launch(void* const* d_in, const int* in_sizes, int n_in,
                              void* d_out, int out_size, void* d_ws, size_t ws_size,
                              hipStream_t stream) {
    const float* u  = (const float*)d_in[0];
    const float* Wr = (const float*)d_in[1];
    const float* Wi = (const float*)d_in[2];
    const float* Wo = (const float*)d_in[3];
    float* out = (float*)d_out;

    float*        xbuf  = (float*)d_ws;
    unsigned int* flags = (unsigned int*)((char*)d_ws + XBUF_BYTES);

    // reset flags (value-based, must start at 0) each replay; xbuf is
    // written-before-read so it needs no reset, but it's inside the range.
    hipMemsetAsync(d_ws, 0, XBUF_BYTES + FLAG_BYTES, stream);

    // ui -> As region of d_out (scan reads it there, then overwrites with a)
    ui_gemm<<<dim3((BB * TT) / 64, NH / 64), 256, 0, stream>>>(u, Wi, out + AS_OFS);

    rnn_scan4<<<BB * WGPB, NTHR, 0, stream>>>(Wr, out, xbuf, flags);

    z_gemv<<<BB, 128, 0, stream>>>(Wo, out);
}

// Round 9
// 5908.041 us; speedup vs baseline: 10.8665x; 1.2812x over previous
//
#include <hip/hip_runtime.h>
#include <stddef.h>
#include <stdint.h>

// Problem dims (fixed by the reference)
#define BB 32
#define TT 2048
#define NI 128
#define NH 512
#define NO 128

// d_out layout (floats): z[BB*NO] | X[BB*TT*NH] | As[BB*TT*NH] | Phis[BB*TT*NH]
#define Z_OFS   0
#define X_OFS   (BB * NO)
#define AS_OFS  (X_OFS + (size_t)BB * TT * NH)
#define PHI_OFS (AS_OFS + (size_t)BB * TT * NH)

// Scan: 4 WGs per batch (128 WGs, 512 thr). Each thread owns one 128-col
// stripe of one Wr row (64 f32x2 pinned regs). Wave 0 owns the exchange.
// Exchange protocol: RELAXED agent atomics only (sc1 stores/loads straight
// to the device coherence point) + explicit vmcnt ordering. NO release/
// acquire -> NO buffer_wbl2 / buffer_inv in the hot loop (the R2..R8 tax).
#define WGPB 4
#define ROWS 128               // rows per WG
#define NTHR 512

// d_ws: xbuf[2][BB][NH] f32 | flags[BB][WGPB] u32 (64 B apart)
#define XBUF_BYTES  (2 * BB * NH * 4)
#define FLAG_STRIDE 16
#define FLAG_BYTES  (BB * WGPB * FLAG_STRIDE * 4)

typedef float f32x2 __attribute__((ext_vector_type(2)));

// ---------------------------------------------------------------------------
// Kernel 1: ui[bt][h] = sum_k u[bt][k] * Wi[h][k]   (written into As region)
// ---------------------------------------------------------------------------
__global__ void __launch_bounds__(256) ui_gemm(const float* __restrict__ u,
                                               const float* __restrict__ Wi,
                                               float* __restrict__ ui_out) {
    __shared__ float Au[64][NI + 1];
    __shared__ float Bw[64][NI + 1];
    const int tid = threadIdx.x;
    const int bt0 = blockIdx.x * 64;
    const int h0  = blockIdx.y * 64;

    for (int idx = tid; idx < 64 * (NI / 4); idx += 256) {
        const int r = idx >> 5;
        const int c = (idx & 31) << 2;
        float4 va = *reinterpret_cast<const float4*>(&u[(size_t)(bt0 + r) * NI + c]);
        Au[r][c + 0] = va.x; Au[r][c + 1] = va.y; Au[r][c + 2] = va.z; Au[r][c + 3] = va.w;
        float4 vb = *reinterpret_cast<const float4*>(&Wi[(size_t)(h0 + r) * NI + c]);
        Bw[r][c + 0] = vb.x; Bw[r][c + 1] = vb.y; Bw[r][c + 2] = vb.z; Bw[r][c + 3] = vb.w;
    }
    __syncthreads();

    const int tx = tid & 15;
    const int ty = tid >> 4;
    float acc[4][4] = {};
    for (int k = 0; k < NI; ++k) {
        float a_[4], b_[4];
#pragma unroll
        for (int i = 0; i < 4; ++i) a_[i] = Au[ty * 4 + i][k];
#pragma unroll
        for (int jj = 0; jj < 4; ++jj) b_[jj] = Bw[tx * 4 + jj][k];
#pragma unroll
        for (int i = 0; i < 4; ++i)
#pragma unroll
            for (int jj = 0; jj < 4; ++jj) acc[i][jj] += a_[i] * b_[jj];
    }
#pragma unroll
    for (int i = 0; i < 4; ++i)
#pragma unroll
        for (int jj = 0; jj < 4; ++jj)
            ui_out[(size_t)(bt0 + ty * 4 + i) * NH + (h0 + tx * 4 + jj)] = acc[i][jj];
}

// ---------------------------------------------------------------------------
// Kernel 2: 4-WG-per-batch scan; relaxed-atomic (sc1) exchange, no wbl2/inv.
// ---------------------------------------------------------------------------
__global__ void __launch_bounds__(NTHR)
rnn_scan4(const float* __restrict__ Wr, float* __restrict__ out,
          float* __restrict__ xbuf, unsigned int* __restrict__ flags) {
    const int blk = blockIdx.x;            // j*32 + b
    const int b   = blk & (BB - 1);
    const int j   = blk >> 5;              // 0..3
    const int h0  = j * ROWS;
    const int tid = threadIdx.x;
    const int q   = tid & 127;             // row within slice
    const int g   = tid >> 7;              // col group: cols [g*128, g*128+128)
    const int l   = tid & 63;              // lane
    const int wv  = tid >> 6;              // wave 0..7

    __shared__ float x_lds[NH];            // 2 KB
    __shared__ float part[WGPB][ROWS];     // 2 KB

    // ---- weights: row h0+q, cols [g*128, g*128+128) -> 64 pinned f32x2
    f32x2 w2[64];
    {
        const float* wrow = Wr + (size_t)(h0 + q) * NH + g * 128;
#pragma unroll
        for (int i = 0; i < 64; ++i)
            w2[i] = *reinterpret_cast<const f32x2*>(&wrow[2 * i]);
#pragma unroll
        for (int i = 0; i < 64; ++i)
            asm volatile("" : "+v"(w2[i]));
    }

    float* __restrict__ Xp  = out + X_OFS   + (size_t)b * TT * NH;
    float* __restrict__ Asp = out + AS_OFS  + (size_t)b * TT * NH;
    float* __restrict__ Php = out + PHI_OFS + (size_t)b * TT * NH;
    unsigned int* __restrict__ fb = flags + (size_t)b * WGPB * FLAG_STRIDE;

    x_lds[tid & (NH - 1)] = 0.0f;          // x0 = 0 (512 threads = NH)

    // ui prefetch for t=0
    f32x2 ui0 = {0.f, 0.f};                // wave 0: rows 2l, 2l+1
    float ui1 = 0.f;                       // waves 2,3: row tid-128
    if (wv == 0) ui0 = *reinterpret_cast<const f32x2*>(&Asp[h0 + 2 * l]);
    else if (wv == 2 || wv == 3) ui1 = Asp[h0 + (tid - 128)];

    // deferred output state (waves 2,3)
    float pa = 0.f, pph = 0.f;
    size_t po = 0;

    __syncthreads();

    for (int t = 0; t < TT; ++t) {
        // ================= phase A: deferred stores + prefetch + FMA ======
        if ((wv == 2 || wv == 3) && t > 0) {
            __builtin_nontemporal_store(pa,  &Asp[po]);
            __builtin_nontemporal_store(pph, &Xp[po]);
            __builtin_nontemporal_store(pph, &Php[po]);
        }
        f32x2 nui0 = {0.f, 0.f};
        float nui1 = 0.f;
        if (t + 1 < TT) {
            if (wv == 0)
                nui0 = *reinterpret_cast<const f32x2*>(
                    &Asp[(size_t)(t + 1) * NH + h0 + 2 * l]);
            else if (wv == 2 || wv == 3)
                nui1 = Asp[(size_t)(t + 1) * NH + h0 + (tid - 128)];
        }

        f32x2 acc = {0.f, 0.f};
        const float* xg = &x_lds[g * 128];  // wave-uniform -> LDS broadcast
#pragma unroll
        for (int i = 0; i < 32; ++i) {
            float4 xv = *reinterpret_cast<const float4*>(&xg[4 * i]);
            acc = __builtin_elementwise_fma(w2[2 * i],     (f32x2){xv.x, xv.y}, acc);
            acc = __builtin_elementwise_fma(w2[2 * i + 1], (f32x2){xv.z, xv.w}, acc);
        }
        part[g][q] = acc.x + acc.y;
        __syncthreads();

        // ================= phase B ========================================
        if (wv == 0) {
            // critical path: reduce 2 rows -> tanh -> relaxed-sc1 exchange
            f32x2 a2 = ui0;
#pragma unroll
            for (int cc = 0; cc < WGPB; ++cc)
                a2 += *reinterpret_cast<const f32x2*>(&part[cc][2 * l]);
            f32x2 ph;
            ph.x = tanhf(a2.x);
            ph.y = tanhf(a2.y);
            *reinterpret_cast<f32x2*>(&x_lds[h0 + 2 * l]) = ph;   // own slice
            if (t + 1 < TT) {
                const size_t bs = (size_t)((t + 1) & 1);
                union { f32x2 f; unsigned long long u; } cv;
                cv.f = ph;
                // data: relaxed atomic u64 store (sc1 -> coherence point)
                __hip_atomic_store(
                    reinterpret_cast<unsigned long long*>(
                        &xbuf[(bs * BB + b) * NH + h0 + 2 * l]),
                    cv.u, __ATOMIC_RELAXED, __HIP_MEMORY_SCOPE_AGENT);
                // order data before flag (producer-side)
                asm volatile("s_waitcnt vmcnt(0)" ::: "memory");
                if (l == 0)
                    __hip_atomic_store(&fb[j * FLAG_STRIDE], (unsigned)(t + 1),
                                       __ATOMIC_RELAXED, __HIP_MEMORY_SCOPE_AGENT);
                if (l < WGPB - 1) {   // lanes 0..2 poll the 3 peers (whole
                    const int jj = l + (l >= j);   // wave waits at the loop)
                    while (__hip_atomic_load(&fb[jj * FLAG_STRIDE],
                                             __ATOMIC_RELAXED,
                                             __HIP_MEMORY_SCOPE_AGENT)
                           < (unsigned)(t + 1)) {}
                }
                asm volatile("" ::: "memory");   // compiler fence only
#pragma unroll
                for (int s = 0; s < WGPB - 1; ++s) {
                    const int jj = s + (s >= j);
                    union { unsigned long long u; f32x2 f; } cu;
                    cu.u = __hip_atomic_load(
                        reinterpret_cast<const unsigned long long*>(
                            &xbuf[(bs * BB + b) * NH + jj * ROWS + 2 * l]),
                        __ATOMIC_RELAXED, __HIP_MEMORY_SCOPE_AGENT);
                    *reinterpret_cast<f32x2*>(&x_lds[jj * ROWS + 2 * l]) = cu.f;
                }
            }
            ui0 = nui0;
        } else if (wv == 2 || wv == 3) {
            // shadow path: duplicate reduce, defer stores to next phase A
            const int rr = tid - 128;
            float a = ui1;
#pragma unroll
            for (int cc = 0; cc < WGPB; ++cc) a += part[cc][rr];
            pa  = a;
            pph = tanhf(a);
            po  = (size_t)t * NH + h0 + rr;
            ui1 = nui1;
        }
        __syncthreads();
    }

    // final deferred outputs (t = TT-1)
    if (wv == 2 || wv == 3) {
        __builtin_nontemporal_store(pa,  &Asp[po]);
        __builtin_nontemporal_store(pph, &Xp[po]);
        __builtin_nontemporal_store(pph, &Php[po]);
    }
}

// ---------------------------------------------------------------------------
// Kernel 3: z[b][o] = sum_h X[b][T-1][h] * Wo[o][h]
// ---------------------------------------------------------------------------
__global__ void __launch_bounds__(128) z_gemv(const float* __restrict__ Wo,
                                              float* __restrict__ out) {
    const int b = blockIdx.x;
    const int o = threadIdx.x;
    __shared__ float xl[NH];
    const float* Xlast = out + X_OFS + (size_t)b * TT * NH + (size_t)(TT - 1) * NH;
    for (int h = threadIdx.x; h < NH; h += 128) xl[h] = Xlast[h];
    __syncthreads();
    float acc = 0.f;
#pragma unroll 4
    for (int h4 = 0; h4 < NH / 4; ++h4) {
        float4 w = *reinterpret_cast<const float4*>(&Wo[(size_t)o * NH + h4 * 4]);
        acc += xl[h4 * 4 + 0] * w.x + xl[h4 * 4 + 1] * w.y +
               xl[h4 * 4 + 2] * w.z + xl[h4 * 4 + 3] * w.w;
    }
    out[Z_OFS + (size_t)b * NO + o] = acc;
}

// ---------------------------------------------------------------------------
extern "C" void kernel_launch(void* const* d_in, const int* in_sizes, int n_in,
                              void* d_out, int out_size, void* d_ws, size_t ws_size,
                              hipStream_t stream) {
    const float* u  = (const float*)d_in[0];
    const float* Wr = (const float*)d_in[1];
    const float* Wi = (const float*)d_in[2];
    const float* Wo = (const float*)d_in[3];
    float* out = (float*)d_out;

    float*        xbuf  = (float*)d_ws;
    unsigned int* flags = (unsigned int*)((char*)d_ws + XBUF_BYTES);

    // reset value-based flags (and xbuf) each replay
    hipMemsetAsync(d_ws, 0, XBUF_BYTES + FLAG_BYTES, stream);

    // ui -> As region of d_out (scan reads it there, then overwrites with a)
    ui_gemm<<<dim3((BB * TT) / 64, NH / 64), 256, 0, stream>>>(u, Wi, out + AS_OFS);

    rnn_scan4<<<BB * WGPB, NTHR, 0, stream>>>(Wr, out, xbuf, flags);

    z_gemv<<<BB, 128, 0, stream>>>(Wo, out);
}

// Round 10
// 4746.462 us; speedup vs baseline: 13.5258x; 1.2447x over previous
//
#include <hip/hip_runtime.h>
#include <stddef.h>
#include <stdint.h>

// Problem dims (fixed by the reference)
#define BB 32
#define TT 2048
#define NI 128
#define NH 512
#define NO 128

// d_out layout (floats): z[BB*NO] | X[BB*TT*NH] | As[BB*TT*NH] | Phis[BB*TT*NH]
#define Z_OFS   0
#define X_OFS   (BB * NO)
#define AS_OFS  (X_OFS + (size_t)BB * TT * NH)
#define PHI_OFS (AS_OFS + (size_t)BB * TT * NH)

// Scan: 4 WGs per batch (128 WGs, 512 thr). Thread (rg=tid>>4, cg=tid&15)
// owns a 4-row x 32-col weight block (64 f32x2 regs) -> x-broadcast LDS reads
// drop 4x vs R9 (8 float4/thread instead of 32). Exchange: (val,tag) packed
// u64 relaxed atomics - no flags, no vmcnt, no wbl2/inv.
#define WGPB 4
#define ROWS 128
#define NTHR 512

// d_ws: xtag[2][BB][NH] u64 (tag in high 32 bits = t+1, val f32 in low)
#define XTAG_BYTES (2 * BB * NH * 8)

typedef float f32x2 __attribute__((ext_vector_type(2)));

// x swizzle: value c lives at c + (c>>5)*4  (36-f32 stride groups, 2-way max)
#define SW(c) ((c) + (((c) >> 5) << 2))

// ---------------------------------------------------------------------------
// Kernel 1: ui[bt][h] = sum_k u[bt][k] * Wi[h][k]   (written into As region)
// ---------------------------------------------------------------------------
__global__ void __launch_bounds__(256) ui_gemm(const float* __restrict__ u,
                                               const float* __restrict__ Wi,
                                               float* __restrict__ ui_out) {
    __shared__ float Au[64][NI + 1];
    __shared__ float Bw[64][NI + 1];
    const int tid = threadIdx.x;
    const int bt0 = blockIdx.x * 64;
    const int h0  = blockIdx.y * 64;

    for (int idx = tid; idx < 64 * (NI / 4); idx += 256) {
        const int r = idx >> 5;
        const int c = (idx & 31) << 2;
        float4 va = *reinterpret_cast<const float4*>(&u[(size_t)(bt0 + r) * NI + c]);
        Au[r][c + 0] = va.x; Au[r][c + 1] = va.y; Au[r][c + 2] = va.z; Au[r][c + 3] = va.w;
        float4 vb = *reinterpret_cast<const float4*>(&Wi[(size_t)(h0 + r) * NI + c]);
        Bw[r][c + 0] = vb.x; Bw[r][c + 1] = vb.y; Bw[r][c + 2] = vb.z; Bw[r][c + 3] = vb.w;
    }
    __syncthreads();

    const int tx = tid & 15;
    const int ty = tid >> 4;
    float acc[4][4] = {};
    for (int k = 0; k < NI; ++k) {
        float a_[4], b_[4];
#pragma unroll
        for (int i = 0; i < 4; ++i) a_[i] = Au[ty * 4 + i][k];
#pragma unroll
        for (int jj = 0; jj < 4; ++jj) b_[jj] = Bw[tx * 4 + jj][k];
#pragma unroll
        for (int i = 0; i < 4; ++i)
#pragma unroll
            for (int jj = 0; jj < 4; ++jj) acc[i][jj] += a_[i] * b_[jj];
    }
#pragma unroll
    for (int i = 0; i < 4; ++i)
#pragma unroll
        for (int jj = 0; jj < 4; ++jj)
            ui_out[(size_t)(bt0 + ty * 4 + i) * NH + (h0 + tx * 4 + jj)] = acc[i][jj];
}

// ---------------------------------------------------------------------------
// Kernel 2: 4-WG-per-batch scan; 4x32 blocks; (val,tag) u64 exchange.
// ---------------------------------------------------------------------------
__global__ void __launch_bounds__(NTHR)
rnn_scan4(const float* __restrict__ Wr, float* __restrict__ out,
          unsigned long long* __restrict__ xtag) {
    const int blk = blockIdx.x;            // j*32 + b
    const int b   = blk & (BB - 1);
    const int j   = blk >> 5;              // 0..3
    const int h0  = j * ROWS;
    const int tid = threadIdx.x;
    const int rg  = tid >> 4;              // 0..31: rows h0+4rg .. +3
    const int cg  = tid & 15;              // cols 32cg .. +32
    const int l   = tid & 63;              // lane
    const int wv  = tid >> 6;              // wave 0..7

    __shared__ float x_swz[576];           // swizzled state, 2.3 KB
    __shared__ float part[16][132];        // padded partials, 8.4 KB

    // ---- weights: 4 rows x 32 cols -> 64 pinned f32x2
    f32x2 w2[64];
    {
        const float* wb = Wr + (size_t)(h0 + 4 * rg) * NH + 32 * cg;
#pragma unroll
        for (int k = 0; k < 4; ++k)
#pragma unroll
            for (int i = 0; i < 8; ++i) {
                float4 t4 = *reinterpret_cast<const float4*>(&wb[(size_t)k * NH + 4 * i]);
                w2[k * 16 + 2 * i]     = (f32x2){t4.x, t4.y};
                w2[k * 16 + 2 * i + 1] = (f32x2){t4.z, t4.w};
            }
#pragma unroll
        for (int i = 0; i < 64; ++i)
            asm volatile("" : "+v"(w2[i]));
    }

    float* __restrict__ Xp  = out + X_OFS   + (size_t)b * TT * NH;
    float* __restrict__ Asp = out + AS_OFS  + (size_t)b * TT * NH;
    float* __restrict__ Php = out + PHI_OFS + (size_t)b * TT * NH;

    for (int m = tid; m < 576; m += NTHR) x_swz[m] = 0.0f;   // x0 = 0

    // ui prefetch for t=0
    f32x2 ui0 = {0.f, 0.f};                // wave 0: rows h0+2l, h0+2l+1
    float ui1 = 0.f;                       // waves 2,3: row h0+(tid-128)
    if (wv == 0) ui0 = *reinterpret_cast<const f32x2*>(&Asp[h0 + 2 * l]);
    else if (wv == 2 || wv == 3) ui1 = Asp[h0 + (tid - 128)];

    // deferred output state (waves 2,3)
    float pa = 0.f, pph = 0.f;
    size_t po = 0;

    __syncthreads();

    for (int t = 0; t < TT; ++t) {
        // ============== phase A: deferred stores + prefetch + FMA =========
        if ((wv == 2 || wv == 3) && t > 0) {
            __builtin_nontemporal_store(pa,  &Asp[po]);
            __builtin_nontemporal_store(pph, &Xp[po]);
            __builtin_nontemporal_store(pph, &Php[po]);
        }
        f32x2 nui0 = {0.f, 0.f};
        float nui1 = 0.f;
        if (t + 1 < TT) {
            if (wv == 0)
                nui0 = *reinterpret_cast<const f32x2*>(
                    &Asp[(size_t)(t + 1) * NH + h0 + 2 * l]);
            else if (wv == 2 || wv == 3)
                nui1 = Asp[(size_t)(t + 1) * NH + h0 + (tid - 128)];
        }

        // FMA: 4 rows x 32 cols; 8 x-float4 reads (4x fewer than R9)
        f32x2 a0 = {0.f, 0.f}, a1 = {0.f, 0.f}, a2 = {0.f, 0.f}, a3 = {0.f, 0.f};
        const float* xg = &x_swz[cg * 36];
#pragma unroll
        for (int i = 0; i < 8; ++i) {
            float4 xv = *reinterpret_cast<const float4*>(&xg[4 * i]);
            f32x2 xa = {xv.x, xv.y};
            f32x2 xb = {xv.z, xv.w};
            a0 = __builtin_elementwise_fma(w2[      2 * i],     xa, a0);
            a0 = __builtin_elementwise_fma(w2[      2 * i + 1], xb, a0);
            a1 = __builtin_elementwise_fma(w2[16  + 2 * i],     xa, a1);
            a1 = __builtin_elementwise_fma(w2[16  + 2 * i + 1], xb, a1);
            a2 = __builtin_elementwise_fma(w2[32  + 2 * i],     xa, a2);
            a2 = __builtin_elementwise_fma(w2[32  + 2 * i + 1], xb, a2);
            a3 = __builtin_elementwise_fma(w2[48  + 2 * i],     xa, a3);
            a3 = __builtin_elementwise_fma(w2[48  + 2 * i + 1], xb, a3);
        }
        {
            float4 pv;
            pv.x = a0.x + a0.y;
            pv.y = a1.x + a1.y;
            pv.z = a2.x + a2.y;
            pv.w = a3.x + a3.y;
            *reinterpret_cast<float4*>(&part[cg][4 * rg]) = pv;   // rows 4rg..+3
        }
        __syncthreads();

        // ============== phase B ===========================================
        if (wv == 0) {
            // critical path: reduce rows 2l,2l+1 -> tanh -> u64 tag exchange
            f32x2 s = ui0;
#pragma unroll
            for (int cc = 0; cc < 16; ++cc)
                s += *reinterpret_cast<const f32x2*>(&part[cc][2 * l]);
            f32x2 ph;
            ph.x = tanhf(s.x);
            ph.y = tanhf(s.y);
            x_swz[SW(h0 + 2 * l)]     = ph.x;   // own slice, local
            x_swz[SW(h0 + 2 * l + 1)] = ph.y;
            if (t + 1 < TT) {
                const unsigned want = (unsigned)(t + 1);
                unsigned long long* xt =
                    xtag + ((size_t)((t + 1) & 1) * BB + b) * NH;
                union { float f; unsigned u; } c0, c1;
                c0.f = ph.x; c1.f = ph.y;
                __hip_atomic_store(&xt[h0 + 2 * l],
                                   ((unsigned long long)want << 32) | c0.u,
                                   __ATOMIC_RELAXED, __HIP_MEMORY_SCOPE_AGENT);
                __hip_atomic_store(&xt[h0 + 2 * l + 1],
                                   ((unsigned long long)want << 32) | c1.u,
                                   __ATOMIC_RELAXED, __HIP_MEMORY_SCOPE_AGENT);
                // poll the 3 remote chunks: rows jj*128+2l, +1 (tag==t+1)
                const int j0 = (j + 1) & 3, j1 = (j + 2) & 3, j2 = (j + 3) & 3;
                const unsigned long long* p0 = &xt[j0 * ROWS + 2 * l];
                const unsigned long long* p1 = &xt[j1 * ROWS + 2 * l];
                const unsigned long long* p2 = &xt[j2 * ROWS + 2 * l];
                unsigned long long r00 = 0, r01 = 0, r10 = 0, r11 = 0, r20 = 0, r21 = 0;
                bool d00 = false, d01 = false, d10 = false, d11 = false,
                     d20 = false, d21 = false;
                do {
                    if (!d00) { r00 = __hip_atomic_load(p0,     __ATOMIC_RELAXED, __HIP_MEMORY_SCOPE_AGENT); d00 = (unsigned)(r00 >> 32) == want; }
                    if (!d01) { r01 = __hip_atomic_load(p0 + 1, __ATOMIC_RELAXED, __HIP_MEMORY_SCOPE_AGENT); d01 = (unsigned)(r01 >> 32) == want; }
                    if (!d10) { r10 = __hip_atomic_load(p1,     __ATOMIC_RELAXED, __HIP_MEMORY_SCOPE_AGENT); d10 = (unsigned)(r10 >> 32) == want; }
                    if (!d11) { r11 = __hip_atomic_load(p1 + 1, __ATOMIC_RELAXED, __HIP_MEMORY_SCOPE_AGENT); d11 = (unsigned)(r11 >> 32) == want; }
                    if (!d20) { r20 = __hip_atomic_load(p2,     __ATOMIC_RELAXED, __HIP_MEMORY_SCOPE_AGENT); d20 = (unsigned)(r20 >> 32) == want; }
                    if (!d21) { r21 = __hip_atomic_load(p2 + 1, __ATOMIC_RELAXED, __HIP_MEMORY_SCOPE_AGENT); d21 = (unsigned)(r21 >> 32) == want; }
                } while (!(d00 && d01 && d10 && d11 && d20 && d21));
                union { unsigned u; float f; } v;
                v.u = (unsigned)r00; x_swz[SW(j0 * ROWS + 2 * l)]     = v.f;
                v.u = (unsigned)r01; x_swz[SW(j0 * ROWS + 2 * l + 1)] = v.f;
                v.u = (unsigned)r10; x_swz[SW(j1 * ROWS + 2 * l)]     = v.f;
                v.u = (unsigned)r11; x_swz[SW(j1 * ROWS + 2 * l + 1)] = v.f;
                v.u = (unsigned)r20; x_swz[SW(j2 * ROWS + 2 * l)]     = v.f;
                v.u = (unsigned)r21; x_swz[SW(j2 * ROWS + 2 * l + 1)] = v.f;
            }
            ui0 = nui0;
        } else if (wv == 2 || wv == 3) {
            // shadow path: duplicate reduce, defer stores to next phase A
            const int rr = tid - 128;
            float a = ui1;
#pragma unroll
            for (int cc = 0; cc < 16; ++cc) a += part[cc][rr];
            pa  = a;
            pph = tanhf(a);
            po  = (size_t)t * NH + h0 + rr;
            ui1 = nui1;
        }
        __syncthreads();
    }

    // final deferred outputs (t = TT-1)
    if (wv == 2 || wv == 3) {
        __builtin_nontemporal_store(pa,  &Asp[po]);
        __builtin_nontemporal_store(pph, &Xp[po]);
        __builtin_nontemporal_store(pph, &Php[po]);
    }
}

// ---------------------------------------------------------------------------
// Kernel 3: z[b][o] = sum_h X[b][T-1][h] * Wo[o][h]
// ---------------------------------------------------------------------------
__global__ void __launch_bounds__(128) z_gemv(const float* __restrict__ Wo,
                                              float* __restrict__ out) {
    const int b = blockIdx.x;
    const int o = threadIdx.x;
    __shared__ float xl[NH];
    const float* Xlast = out + X_OFS + (size_t)b * TT * NH + (size_t)(TT - 1) * NH;
    for (int h = threadIdx.x; h < NH; h += 128) xl[h] = Xlast[h];
    __syncthreads();
    float acc = 0.f;
#pragma unroll 4
    for (int h4 = 0; h4 < NH / 4; ++h4) {
        float4 w = *reinterpret_cast<const float4*>(&Wo[(size_t)o * NH + h4 * 4]);
        acc += xl[h4 * 4 + 0] * w.x + xl[h4 * 4 + 1] * w.y +
               xl[h4 * 4 + 2] * w.z + xl[h4 * 4 + 3] * w.w;
    }
    out[Z_OFS + (size_t)b * NO + o] = acc;
}

// ---------------------------------------------------------------------------
extern "C" void kernel_launch(void* const* d_in, const int* in_sizes, int n_in,
                              void* d_out, int out_size, void* d_ws, size_t ws_size,
                              hipStream_t stream) {
    const float* u  = (const float*)d_in[0];
    const float* Wr = (const float*)d_in[1];
    const float* Wi = (const float*)d_in[2];
    const float* Wo = (const float*)d_in[3];
    float* out = (float*)d_out;

    unsigned long long* xtag = (unsigned long long*)d_ws;

    // reset tags each replay (stale tags from a previous replay would alias)
    hipMemsetAsync(d_ws, 0, XTAG_BYTES, stream);

    // ui -> As region of d_out (scan reads it there, then overwrites with a)
    ui_gemm<<<dim3((BB * TT) / 64, NH / 64), 256, 0, stream>>>(u, Wi, out + AS_OFS);

    rnn_scan4<<<BB * WGPB, NTHR, 0, stream>>>(Wr, out, xtag);

    z_gemv<<<BB, 128, 0, stream>>>(Wo, out);
}

// Round 11
// 4039.832 us; speedup vs baseline: 15.8917x; 1.1749x over previous
//
#include <hip/hip_runtime.h>
#include <stddef.h>
#include <stdint.h>

// Problem dims (fixed by the reference)
#define BB 32
#define TT 2048
#define NI 128
#define NH 512
#define NO 128

// d_out layout (floats): z[BB*NO] | X[BB*TT*NH] | As[BB*TT*NH] | Phis[BB*TT*NH]
#define Z_OFS   0
#define X_OFS   (BB * NO)
#define AS_OFS  (X_OFS + (size_t)BB * TT * NH)
#define PHI_OFS (AS_OFS + (size_t)BB * TT * NH)

// Scan: 4 WGs per batch (128 WGs, 512 thr). Thread (rg=tid>>4, cg=tid&15)
// owns a 4-row x 32-col weight block (64 f32x2 regs). Exchange: (val,tag)
// packed u64 relaxed atomics; PARALLEL poll - wave w in {1,2,3} polls remote
// slice (j+w)&3 while wave 0 produces; waves 4,5 duplicate the reduce for
// output streaming (deferred one phase).
#define WGPB 4
#define ROWS 128
#define NTHR 512

// d_ws: xtag[2][BB][NH] u64 (tag in high 32 bits = t+1, val f32 in low)
#define XTAG_BYTES (2 * BB * NH * 8)

typedef float f32x2 __attribute__((ext_vector_type(2)));

// x swizzle: value c lives at c + (c>>5)*4  (36-f32 stride groups)
#define SW(c) ((c) + (((c) >> 5) << 2))

__device__ __forceinline__ float fast_tanh(float x) {
    // tanh(x) = 1 - 2/(e^{2x}+1), e^{2x} = exp2(2*log2e*x). ~5 VALU.
    // exp2(-inf)->0 gives -1; exp2(+big)->+inf gives 1-0=1. Monotone, ~2e-7.
    float e = __builtin_exp2f(x * 2.8853900817779268f);
    return 1.0f - 2.0f * __builtin_amdgcn_rcpf(e + 1.0f);
}

// ---------------------------------------------------------------------------
// Kernel 1: ui[bt][h] = sum_k u[bt][k] * Wi[h][k]   (written into As region)
// ---------------------------------------------------------------------------
__global__ void __launch_bounds__(256) ui_gemm(const float* __restrict__ u,
                                               const float* __restrict__ Wi,
                                               float* __restrict__ ui_out) {
    __shared__ float Au[64][NI + 1];
    __shared__ float Bw[64][NI + 1];
    const int tid = threadIdx.x;
    const int bt0 = blockIdx.x * 64;
    const int h0  = blockIdx.y * 64;

    for (int idx = tid; idx < 64 * (NI / 4); idx += 256) {
        const int r = idx >> 5;
        const int c = (idx & 31) << 2;
        float4 va = *reinterpret_cast<const float4*>(&u[(size_t)(bt0 + r) * NI + c]);
        Au[r][c + 0] = va.x; Au[r][c + 1] = va.y; Au[r][c + 2] = va.z; Au[r][c + 3] = va.w;
        float4 vb = *reinterpret_cast<const float4*>(&Wi[(size_t)(h0 + r) * NI + c]);
        Bw[r][c + 0] = vb.x; Bw[r][c + 1] = vb.y; Bw[r][c + 2] = vb.z; Bw[r][c + 3] = vb.w;
    }
    __syncthreads();

    const int tx = tid & 15;
    const int ty = tid >> 4;
    float acc[4][4] = {};
    for (int k = 0; k < NI; ++k) {
        float a_[4], b_[4];
#pragma unroll
        for (int i = 0; i < 4; ++i) a_[i] = Au[ty * 4 + i][k];
#pragma unroll
        for (int jj = 0; jj < 4; ++jj) b_[jj] = Bw[tx * 4 + jj][k];
#pragma unroll
        for (int i = 0; i < 4; ++i)
#pragma unroll
            for (int jj = 0; jj < 4; ++jj) acc[i][jj] += a_[i] * b_[jj];
    }
#pragma unroll
    for (int i = 0; i < 4; ++i)
#pragma unroll
        for (int jj = 0; jj < 4; ++jj)
            ui_out[(size_t)(bt0 + ty * 4 + i) * NH + (h0 + tx * 4 + jj)] = acc[i][jj];
}

// ---------------------------------------------------------------------------
// Kernel 2: 4-WG-per-batch scan; parallel-poll (val,tag) u64 exchange.
// ---------------------------------------------------------------------------
__global__ void __launch_bounds__(NTHR)
rnn_scan4(const float* __restrict__ Wr, float* __restrict__ out,
          unsigned long long* __restrict__ xtag) {
    const int blk = blockIdx.x;            // j*32 + b
    const int b   = blk & (BB - 1);
    const int j   = blk >> 5;              // 0..3
    const int h0  = j * ROWS;
    const int tid = threadIdx.x;
    const int rg  = tid >> 4;              // 0..31: rows h0+4rg .. +3
    const int cg  = tid & 15;              // cols 32cg .. +32
    const int l   = tid & 63;              // lane
    const int wv  = tid >> 6;              // wave 0..7

    __shared__ float x_swz[576];           // swizzled state
    __shared__ float part[16][132];        // padded partials

    // ---- weights: 4 rows x 32 cols -> 64 pinned f32x2
    f32x2 w2[64];
    {
        const float* wb = Wr + (size_t)(h0 + 4 * rg) * NH + 32 * cg;
#pragma unroll
        for (int k = 0; k < 4; ++k)
#pragma unroll
            for (int i = 0; i < 8; ++i) {
                float4 t4 = *reinterpret_cast<const float4*>(&wb[(size_t)k * NH + 4 * i]);
                w2[k * 16 + 2 * i]     = (f32x2){t4.x, t4.y};
                w2[k * 16 + 2 * i + 1] = (f32x2){t4.z, t4.w};
            }
#pragma unroll
        for (int i = 0; i < 64; ++i)
            asm volatile("" : "+v"(w2[i]));
    }

    float* __restrict__ Xp  = out + X_OFS   + (size_t)b * TT * NH;
    float* __restrict__ Asp = out + AS_OFS  + (size_t)b * TT * NH;
    float* __restrict__ Php = out + PHI_OFS + (size_t)b * TT * NH;

    for (int m = tid; m < 576; m += NTHR) x_swz[m] = 0.0f;   // x0 = 0

    // ui prefetch for t=0
    f32x2 ui0 = {0.f, 0.f};                // wave 0: rows h0+2l, h0+2l+1
    float ui1 = 0.f;                       // waves 4,5: row h0+(tid-256)
    if (wv == 0) ui0 = *reinterpret_cast<const f32x2*>(&Asp[h0 + 2 * l]);
    else if (wv == 4 || wv == 5) ui1 = Asp[h0 + (tid - 256)];

    // deferred output state (waves 4,5)
    float pa = 0.f, pph = 0.f;
    size_t po = 0;

    __syncthreads();

    for (int t = 0; t < TT; ++t) {
        // ============== phase A: deferred stores + prefetch + FMA =========
        if ((wv == 4 || wv == 5) && t > 0) {
            __builtin_nontemporal_store(pa,  &Asp[po]);
            __builtin_nontemporal_store(pph, &Xp[po]);
            __builtin_nontemporal_store(pph, &Php[po]);
        }
        f32x2 nui0 = {0.f, 0.f};
        float nui1 = 0.f;
        if (t + 1 < TT) {
            if (wv == 0)
                nui0 = *reinterpret_cast<const f32x2*>(
                    &Asp[(size_t)(t + 1) * NH + h0 + 2 * l]);
            else if (wv == 4 || wv == 5)
                nui1 = Asp[(size_t)(t + 1) * NH + h0 + (tid - 256)];
        }

        // FMA: 4 rows x 32 cols; 8 x-float4 reads
        f32x2 a0 = {0.f, 0.f}, a1 = {0.f, 0.f}, a2 = {0.f, 0.f}, a3 = {0.f, 0.f};
        const float* xg = &x_swz[cg * 36];
#pragma unroll
        for (int i = 0; i < 8; ++i) {
            float4 xv = *reinterpret_cast<const float4*>(&xg[4 * i]);
            f32x2 xa = {xv.x, xv.y};
            f32x2 xb = {xv.z, xv.w};
            a0 = __builtin_elementwise_fma(w2[      2 * i],     xa, a0);
            a0 = __builtin_elementwise_fma(w2[      2 * i + 1], xb, a0);
            a1 = __builtin_elementwise_fma(w2[16  + 2 * i],     xa, a1);
            a1 = __builtin_elementwise_fma(w2[16  + 2 * i + 1], xb, a1);
            a2 = __builtin_elementwise_fma(w2[32  + 2 * i],     xa, a2);
            a2 = __builtin_elementwise_fma(w2[32  + 2 * i + 1], xb, a2);
            a3 = __builtin_elementwise_fma(w2[48  + 2 * i],     xa, a3);
            a3 = __builtin_elementwise_fma(w2[48  + 2 * i + 1], xb, a3);
        }
        {
            float4 pv;
            pv.x = a0.x + a0.y;
            pv.y = a1.x + a1.y;
            pv.z = a2.x + a2.y;
            pv.w = a3.x + a3.y;
            *reinterpret_cast<float4*>(&part[cg][4 * rg]) = pv;   // rows 4rg..+3
        }
        __syncthreads();

        // ============== phase B (wave-role split) =========================
        if (wv == 0) {
            // produce: reduce rows 2l,2l+1 -> tanh -> own LDS + MALL store
            f32x2 s = ui0;
#pragma unroll
            for (int cc = 0; cc < 16; ++cc)
                s += *reinterpret_cast<const f32x2*>(&part[cc][2 * l]);
            f32x2 ph;
            ph.x = fast_tanh(s.x);
            ph.y = fast_tanh(s.y);
            x_swz[SW(h0 + 2 * l)]     = ph.x;
            x_swz[SW(h0 + 2 * l + 1)] = ph.y;
            if (t + 1 < TT) {
                const unsigned want = (unsigned)(t + 1);
                unsigned long long* xt =
                    xtag + ((size_t)((t + 1) & 1) * BB + b) * NH;
                union { float f; unsigned u; } c0, c1;
                c0.f = ph.x; c1.f = ph.y;
                __hip_atomic_store(&xt[h0 + 2 * l],
                                   ((unsigned long long)want << 32) | c0.u,
                                   __ATOMIC_RELAXED, __HIP_MEMORY_SCOPE_AGENT);
                __hip_atomic_store(&xt[h0 + 2 * l + 1],
                                   ((unsigned long long)want << 32) | c1.u,
                                   __ATOMIC_RELAXED, __HIP_MEMORY_SCOPE_AGENT);
            }
            ui0 = nui0;
        } else if (wv <= 3) {
            // consume: wave wv polls remote slice (j+wv)&3, 2 u64 per lane
            if (t + 1 < TT) {
                const unsigned want = (unsigned)(t + 1);
                const int jj = (j + wv) & 3;
                const unsigned long long* p =
                    xtag + ((size_t)((t + 1) & 1) * BB + b) * NH + jj * ROWS + 2 * l;
                unsigned long long r0 = 0, r1 = 0;
                bool d0 = false, d1 = false;
                do {
                    if (!d0) { r0 = __hip_atomic_load(p,     __ATOMIC_RELAXED, __HIP_MEMORY_SCOPE_AGENT); d0 = (unsigned)(r0 >> 32) == want; }
                    if (!d1) { r1 = __hip_atomic_load(p + 1, __ATOMIC_RELAXED, __HIP_MEMORY_SCOPE_AGENT); d1 = (unsigned)(r1 >> 32) == want; }
                } while (!(d0 && d1));
                union { unsigned u; float f; } v0, v1;
                v0.u = (unsigned)r0;
                v1.u = (unsigned)r1;
                x_swz[SW(jj * ROWS + 2 * l)]     = v0.f;
                x_swz[SW(jj * ROWS + 2 * l + 1)] = v1.f;
            }
        } else if (wv == 4 || wv == 5) {
            // output shadow: duplicate reduce, defer stores to next phase A
            const int rr = tid - 256;
            float a = ui1;
#pragma unroll
            for (int cc = 0; cc < 16; ++cc) a += part[cc][rr];
            pa  = a;
            pph = fast_tanh(a);
            po  = (size_t)t * NH + h0 + rr;
            ui1 = nui1;
        }
        __syncthreads();
    }

    // final deferred outputs (t = TT-1)
    if (wv == 4 || wv == 5) {
        __builtin_nontemporal_store(pa,  &Asp[po]);
        __builtin_nontemporal_store(pph, &Xp[po]);
        __builtin_nontemporal_store(pph, &Php[po]);
    }
}

// ---------------------------------------------------------------------------
// Kernel 3: z[b][o] = sum_h X[b][T-1][h] * Wo[o][h]
// ---------------------------------------------------------------------------
__global__ void __launch_bounds__(128) z_gemv(const float* __restrict__ Wo,
                                              float* __restrict__ out) {
    const int b = blockIdx.x;
    const int o = threadIdx.x;
    __shared__ float xl[NH];
    const float* Xlast = out + X_OFS + (size_t)b * TT * NH + (size_t)(TT - 1) * NH;
    for (int h = threadIdx.x; h < NH; h += 128) xl[h] = Xlast[h];
    __syncthreads();
    float acc = 0.f;
#pragma unroll 4
    for (int h4 = 0; h4 < NH / 4; ++h4) {
        float4 w = *reinterpret_cast<const float4*>(&Wo[(size_t)o * NH + h4 * 4]);
        acc += xl[h4 * 4 + 0] * w.x + xl[h4 * 4 + 1] * w.y +
               xl[h4 * 4 + 2] * w.z + xl[h4 * 4 + 3] * w.w;
    }
    out[Z_OFS + (size_t)b * NO + o] = acc;
}

// ---------------------------------------------------------------------------
extern "C" void kernel_launch(void* const* d_in, const int* in_sizes, int n_in,
                              void* d_out, int out_size, void* d_ws, size_t ws_size,
                              hipStream_t stream) {
    const float* u  = (const float*)d_in[0];
    const float* Wr = (const float*)d_in[1];
    const float* Wi = (const float*)d_in[2];
    const float* Wo = (const float*)d_in[3];
    float* out = (float*)d_out;

    unsigned long long* xtag = (unsigned long long*)d_ws;

    // reset tags each replay (stale tags from a previous replay would alias)
    hipMemsetAsync(d_ws, 0, XTAG_BYTES, stream);

    // ui -> As region of d_out (scan reads it there, then overwrites with a)
    ui_gemm<<<dim3((BB * TT) / 64, NH / 64), 256, 0, stream>>>(u, Wi, out + AS_OFS);

    rnn_scan4<<<BB * WGPB, NTHR, 0, stream>>>(Wr, out, xtag);

    z_gemv<<<BB, 128, 0, stream>>>(Wo, out);
}

// Round 12
// 3173.728 us; speedup vs baseline: 20.2285x; 1.2729x over previous
//
#include <hip/hip_runtime.h>
#include <stddef.h>
#include <stdint.h>

// Problem dims (fixed by the reference)
#define BB 32
#define TT 2048
#define NI 128
#define NH 512
#define NO 128

// d_out layout (floats): z[BB*NO] | X[BB*TT*NH] | As[BB*TT*NH] | Phis[BB*TT*NH]
#define Z_OFS   0
#define X_OFS   (BB * NO)
#define AS_OFS  (X_OFS + (size_t)BB * TT * NH)
#define PHI_OFS (AS_OFS + (size_t)BB * TT * NH)

// Scan: 4 WGs per batch (128 WGs, 512 thr). Thread (rg=tid>>4, cg=tid&15)
// owns a 4-row x 32-col weight block (64 f32x2 regs).
// Per step: FMA -> in-wave butterfly reduce over cg (DPP/swizzle, no LDS
// round-trip, no extra barrier) -> lanes cg<4 produce row 4rg+cg (tanh +
// MALL (val,tag) store) -> lanes tid<384 poll one remote u64 each ->
// ONE barrier. x state double-buffered in LDS (FMA reads buf[t&1], writers
// fill buf[(t+1)&1] concurrently).
#define WGPB 4
#define ROWS 128
#define NTHR 512

// d_ws: xtag[2][BB][NH] u64 (tag in high 32 bits = t+1, val f32 in low)
#define XTAG_BYTES (2 * BB * NH * 8)

typedef float f32x2 __attribute__((ext_vector_type(2)));

// x swizzle within a buffer: value c lives at c + (c>>5)*4 (36-f32 groups)
#define SW(c) ((c) + (((c) >> 5) << 2))
#define XBUF 576

__device__ __forceinline__ float fast_tanh(float x) {
    float e = __builtin_exp2f(x * 2.8853900817779268f);
    return 1.0f - 2.0f * __builtin_amdgcn_rcpf(e + 1.0f);
}

// ---------------------------------------------------------------------------
// Kernel 1: ui[bt][h] = sum_k u[bt][k] * Wi[h][k]   (written into As region)
// ---------------------------------------------------------------------------
__global__ void __launch_bounds__(256) ui_gemm(const float* __restrict__ u,
                                               const float* __restrict__ Wi,
                                               float* __restrict__ ui_out) {
    __shared__ float Au[64][NI + 1];
    __shared__ float Bw[64][NI + 1];
    const int tid = threadIdx.x;
    const int bt0 = blockIdx.x * 64;
    const int h0  = blockIdx.y * 64;

    for (int idx = tid; idx < 64 * (NI / 4); idx += 256) {
        const int r = idx >> 5;
        const int c = (idx & 31) << 2;
        float4 va = *reinterpret_cast<const float4*>(&u[(size_t)(bt0 + r) * NI + c]);
        Au[r][c + 0] = va.x; Au[r][c + 1] = va.y; Au[r][c + 2] = va.z; Au[r][c + 3] = va.w;
        float4 vb = *reinterpret_cast<const float4*>(&Wi[(size_t)(h0 + r) * NI + c]);
        Bw[r][c + 0] = vb.x; Bw[r][c + 1] = vb.y; Bw[r][c + 2] = vb.z; Bw[r][c + 3] = vb.w;
    }
    __syncthreads();

    const int tx = tid & 15;
    const int ty = tid >> 4;
    float acc[4][4] = {};
    for (int k = 0; k < NI; ++k) {
        float a_[4], b_[4];
#pragma unroll
        for (int i = 0; i < 4; ++i) a_[i] = Au[ty * 4 + i][k];
#pragma unroll
        for (int jj = 0; jj < 4; ++jj) b_[jj] = Bw[tx * 4 + jj][k];
#pragma unroll
        for (int i = 0; i < 4; ++i)
#pragma unroll
            for (int jj = 0; jj < 4; ++jj) acc[i][jj] += a_[i] * b_[jj];
    }
#pragma unroll
    for (int i = 0; i < 4; ++i)
#pragma unroll
        for (int jj = 0; jj < 4; ++jj)
            ui_out[(size_t)(bt0 + ty * 4 + i) * NH + (h0 + tx * 4 + jj)] = acc[i][jj];
}

// ---------------------------------------------------------------------------
// Kernel 2: 4-WG-per-batch scan; in-wave reduce; 1 barrier/step.
// ---------------------------------------------------------------------------
__global__ void __launch_bounds__(NTHR)
rnn_scan4(const float* __restrict__ Wr, float* __restrict__ out,
          unsigned long long* __restrict__ xtag) {
    const int blk = blockIdx.x;            // j*32 + b
    const int b   = blk & (BB - 1);
    const int j   = blk >> 5;              // 0..3
    const int h0  = j * ROWS;
    const int tid = threadIdx.x;
    const int rg  = tid >> 4;              // 0..31: rows h0+4rg .. +3
    const int cg  = tid & 15;              // cols 32cg .. +32

    __shared__ float x_swz[2][XBUF];       // double-buffered swizzled state

    // ---- weights: 4 rows x 32 cols -> 64 pinned f32x2
    f32x2 w2[64];
    {
        const float* wb = Wr + (size_t)(h0 + 4 * rg) * NH + 32 * cg;
#pragma unroll
        for (int k = 0; k < 4; ++k)
#pragma unroll
            for (int i = 0; i < 8; ++i) {
                float4 t4 = *reinterpret_cast<const float4*>(&wb[(size_t)k * NH + 4 * i]);
                w2[k * 16 + 2 * i]     = (f32x2){t4.x, t4.y};
                w2[k * 16 + 2 * i + 1] = (f32x2){t4.z, t4.w};
            }
#pragma unroll
        for (int i = 0; i < 64; ++i)
            asm volatile("" : "+v"(w2[i]));
    }

    float* __restrict__ Xp  = out + X_OFS   + (size_t)b * TT * NH;
    float* __restrict__ Asp = out + AS_OFS  + (size_t)b * TT * NH;
    float* __restrict__ Php = out + PHI_OFS + (size_t)b * TT * NH;

    for (int m = tid; m < XBUF; m += NTHR) {    // x0 = 0
        x_swz[0][m] = 0.0f;
        x_swz[1][m] = 0.0f;
    }

    // producer lanes: cg<4 own row h0+4rg+cg
    const bool prod  = (cg < 4);
    const int  myrow = 4 * rg + cg;             // row within slice (if prod)

    // poller lanes: tid<384 own one remote u64
    const bool poll  = (tid < 384);
    const int  pjj   = (j + 1 + (tid >> 7)) & 3;
    const int  pidx  = tid & 127;

    // ui prefetch for t=0 (producer lanes)
    float uival = 0.0f;
    if (prod) uival = Asp[h0 + myrow];

    // deferred output state (producer lanes)
    float da = 0.f, dph = 0.f;
    size_t dpo = 0;

    __syncthreads();

    for (int t = 0; t < TT; ++t) {
        const int cur = t & 1, nxt = cur ^ 1;

        // ---- deferred output stores (for step t-1) + next-ui prefetch
        float nui = 0.0f;
        if (prod) {
            if (t > 0) {
                __builtin_nontemporal_store(da,  &Asp[dpo]);
                __builtin_nontemporal_store(dph, &Xp[dpo]);
                __builtin_nontemporal_store(dph, &Php[dpo]);
            }
            if (t + 1 < TT) nui = Asp[(size_t)(t + 1) * NH + h0 + myrow];
        }

        // ---- FMA: 4 rows x 32 cols; 8 x-float4 reads from buf[cur]
        f32x2 a0 = {0.f, 0.f}, a1 = {0.f, 0.f}, a2 = {0.f, 0.f}, a3 = {0.f, 0.f};
        const float* xg = &x_swz[cur][cg * 36];
#pragma unroll
        for (int i = 0; i < 8; ++i) {
            float4 xv = *reinterpret_cast<const float4*>(&xg[4 * i]);
            f32x2 xa = {xv.x, xv.y};
            f32x2 xb = {xv.z, xv.w};
            a0 = __builtin_elementwise_fma(w2[      2 * i],     xa, a0);
            a0 = __builtin_elementwise_fma(w2[      2 * i + 1], xb, a0);
            a1 = __builtin_elementwise_fma(w2[16  + 2 * i],     xa, a1);
            a1 = __builtin_elementwise_fma(w2[16  + 2 * i + 1], xb, a1);
            a2 = __builtin_elementwise_fma(w2[32  + 2 * i],     xa, a2);
            a2 = __builtin_elementwise_fma(w2[32  + 2 * i + 1], xb, a2);
            a3 = __builtin_elementwise_fma(w2[48  + 2 * i],     xa, a3);
            a3 = __builtin_elementwise_fma(w2[48  + 2 * i + 1], xb, a3);
        }
        float4 pv;
        pv.x = a0.x + a0.y;
        pv.y = a1.x + a1.y;
        pv.z = a2.x + a2.y;
        pv.w = a3.x + a3.y;

        // ---- in-wave butterfly over cg (masks 1,2 = DPP-rate; 4,8 = swizzle)
#pragma unroll
        for (int mask = 1; mask <= 8; mask <<= 1) {
            pv.x += __shfl_xor(pv.x, mask);
            pv.y += __shfl_xor(pv.y, mask);
            pv.z += __shfl_xor(pv.z, mask);
            pv.w += __shfl_xor(pv.w, mask);
        }

        // ---- produce: lanes cg<4 own row 4rg+cg
        if (prod) {
            float s = (cg == 0) ? pv.x : (cg == 1) ? pv.y : (cg == 2) ? pv.z : pv.w;
            s += uival;
            const float phi = fast_tanh(s);
            x_swz[nxt][SW(h0 + myrow)] = phi;
            if (t + 1 < TT) {
                union { float f; unsigned u; } cv;
                cv.f = phi;
                __hip_atomic_store(
                    &xtag[((size_t)(nxt) * BB + b) * NH + h0 + myrow],
                    ((unsigned long long)(unsigned)(t + 1) << 32) | cv.u,
                    __ATOMIC_RELAXED, __HIP_MEMORY_SCOPE_AGENT);
            }
            da  = s;
            dph = phi;
            dpo = (size_t)t * NH + h0 + myrow;
            uival = nui;
        }

        // ---- poll: lanes tid<384 fetch one remote value
        if (poll && t + 1 < TT) {
            const unsigned want = (unsigned)(t + 1);
            const unsigned long long* p =
                xtag + ((size_t)(nxt) * BB + b) * NH + pjj * ROWS + pidx;
            unsigned long long r;
            do {
                r = __hip_atomic_load(p, __ATOMIC_RELAXED, __HIP_MEMORY_SCOPE_AGENT);
            } while ((unsigned)(r >> 32) != want);
            union { unsigned u; float f; } v;
            v.u = (unsigned)r;
            x_swz[nxt][SW(pjj * ROWS + pidx)] = v.f;
        }
        __syncthreads();
    }

    // final deferred outputs (t = TT-1)
    if (prod) {
        __builtin_nontemporal_store(da,  &Asp[dpo]);
        __builtin_nontemporal_store(dph, &Xp[dpo]);
        __builtin_nontemporal_store(dph, &Php[dpo]);
    }
}

// ---------------------------------------------------------------------------
// Kernel 3: z[b][o] = sum_h X[b][T-1][h] * Wo[o][h]
// ---------------------------------------------------------------------------
__global__ void __launch_bounds__(128) z_gemv(const float* __restrict__ Wo,
                                              float* __restrict__ out) {
    const int b = blockIdx.x;
    const int o = threadIdx.x;
    __shared__ float xl[NH];
    const float* Xlast = out + X_OFS + (size_t)b * TT * NH + (size_t)(TT - 1) * NH;
    for (int h = threadIdx.x; h < NH; h += 128) xl[h] = Xlast[h];
    __syncthreads();
    float acc = 0.f;
#pragma unroll 4
    for (int h4 = 0; h4 < NH / 4; ++h4) {
        float4 w = *reinterpret_cast<const float4*>(&Wo[(size_t)o * NH + h4 * 4]);
        acc += xl[h4 * 4 + 0] * w.x + xl[h4 * 4 + 1] * w.y +
               xl[h4 * 4 + 2] * w.z + xl[h4 * 4 + 3] * w.w;
    }
    out[Z_OFS + (size_t)b * NO + o] = acc;
}

// ---------------------------------------------------------------------------
extern "C" void kernel_launch(void* const* d_in, const int* in_sizes, int n_in,
                              void* d_out, int out_size, void* d_ws, size_t ws_size,
                              hipStream_t stream) {
    const float* u  = (const float*)d_in[0];
    const float* Wr = (const float*)d_in[1];
    const float* Wi = (const float*)d_in[2];
    const float* Wo = (const float*)d_in[3];
    float* out = (float*)d_out;

    unsigned long long* xtag = (unsigned long long*)d_ws;

    // reset tags each replay (stale tags from a previous replay would alias)
    hipMemsetAsync(d_ws, 0, XTAG_BYTES, stream);

    // ui -> As region of d_out (scan reads it there, then overwrites with a)
    ui_gemm<<<dim3((BB * TT) / 64, NH / 64), 256, 0, stream>>>(u, Wi, out + AS_OFS);

    rnn_scan4<<<BB * WGPB, NTHR, 0, stream>>>(Wr, out, xtag);

    z_gemv<<<BB, 128, 0, stream>>>(Wo, out);
}